// Round 9
// baseline (572.267 us; speedup 1.0000x reference)
//
#include <hip/hip_runtime.h>

// Modular readout: 8 modules, each h = relu(x_m @ W1_m^T + b1_m); y_m = h @ W2_m^T + b2_m
// x [8192,4096] fp32; W1 [4096,4096] fp32 block-diag (8x 512x512); W2 [80,4096] fp32 block-diag
// out [8192,80] fp32 row-major (module-major columns).
//
// R14: DIAGNOSTIC ROUND 2. R13's ablations were clipped out of the top-5 by the harness's
//      512 MiB workspace re-poison fills (77us @ 7.0 TB/s, inside the replayed graph!).
//      Facts learned: (a) ~170us of dur_us is harness overhead (fills/restores/init/cvt) ->
//      total floor ~210-230us; (b) ALL ablations AND fused_pipe ran <76.3us (fused was 86-90
//      in every prior round -> rule-#19 codegen perturbation or warming); ablations sum ~100us.
//      This round: rep-ablated variants that MUST exceed the 77us fills:
//        abl1_stage x3 : staging+waits+barriers only          -> stage cost = dur/3
//        abl3_noepi x3 : full K-loop, epilogue = acc dump      -> loop cost  = dur/3
//        abl4_epi   x6 : epilogue only (acc=0, atomics -> ws)  -> epi cost   = dur/6
//      Scoring path unchanged (R8-exact fused_pipe). dur_us deliberately inflated ~700-900.
//      Decision tree: epi-heavy -> rewrite epilogue (ds_write_b64 transposed-LDS, no atomics);
//      stage-heavy -> bf16-x pre-pass into the 512MB ws; both small -> fuse across blocks.

#define NMOD 8
#define DIM 512
#define OSZ 10
#define BATCH 8192
#define D_IN 4096
#define D_OUT 80
#define BM 128
#define BN 256
#define BK 32
#define NK (DIM / BK)     // 16

#define ASTRIDE 40        // ldsA row stride (shorts); 80B, 16B-aligned, conflict-free
#define HSTRIDE 264       // ldsH row stride (shorts); 528B = 33*16 -> aligned + conflict-free
#define A_SZ 5120         // 128*40 shorts per A buffer (10240 B)
#define B_SZ 8192         // 256*32 shorts per B buffer (16384 B, unpadded: DMA lane-contiguous dst)

// legacy tier-C sizes
#define LDSA_SZ 5120
#define LDSB_SZ 8192

#define VMCNT(n) asm volatile("s_waitcnt vmcnt(" #n ")" ::: "memory")
#define LGKM0()  asm volatile("s_waitcnt lgkmcnt(0)" ::: "memory")
#define MEMFENCE() asm volatile("" ::: "memory")

typedef __attribute__((ext_vector_type(8))) short short8;   // 8 bf16 MFMA A/B frag
typedef __attribute__((ext_vector_type(4))) float float4v;  // MFMA C/D frag
typedef __attribute__((ext_vector_type(4))) unsigned int uint4v;

__device__ __forceinline__ unsigned short f2bf(float f) {
    unsigned int u = __builtin_bit_cast(unsigned int, f);
    u += 0x7fffu + ((u >> 16) & 1u);   // RNE
    return (unsigned short)(u >> 16);
}

__device__ __forceinline__ unsigned int pk2(float a, float b) {
    unsigned int r;
    asm("v_cvt_pk_bf16_f32 %0, %1, %2" : "=v"(r) : "v"(a), "v"(b));
    return r;
}

// packed f32x8 -> bf16x8 via HW cvt_pk (RNE, same numerics as f2bf)
__device__ __forceinline__ short8 cvt8(float4 a, float4 b) {
    uint4v u = {pk2(a.x, a.y), pk2(a.z, a.w), pk2(b.x, b.y), pk2(b.z, b.w)};
    return __builtin_bit_cast(short8, u);
}

// ------- init: out = broadcast b2 (atomicAdd accumulation base) -------
__global__ void init_out_kernel(const float* __restrict__ b2, float* __restrict__ out) {
    int idx = blockIdx.x * 256 + threadIdx.x;            // 2560*256 = 655360 = 8192*80
    out[idx] = b2[idx % D_OUT];
}

// ------- tier B: gather W1 diag blocks -> w1b[8][512][512] bf16 (4 MB) -------
__global__ void cvt_w_kernel(const float* __restrict__ W1, ushort* __restrict__ w1b) {
    int j = blockIdx.x * 256 + threadIdx.x;              // 2048*256 = 524288 float4 jobs
    int mm = j >> 16, rem = j & 65535, r = rem >> 7, c4 = rem & 127;
    float4 v = *(const float4*)(W1 + (size_t)(mm * DIM + r) * D_IN + mm * DIM + c4 * 4);
    *(ushort4*)(w1b + (size_t)mm * DIM * DIM + r * DIM + c4 * 4) =
        make_ushort4(f2bf(v.x), f2bf(v.y), f2bf(v.z), f2bf(v.w));
}

// ---------------- R8 body, templated for ablation ----------------
// V=0 full (writes out); V=1 stage-only x RP; V=3 no-epilogue x RP; V=4 epilogue-only x RP
// (V=4: acc=0, atomics land in `out` which the wrapper points at ws).
template <int V, int RP>
__device__ __forceinline__ void fused_body(const float* __restrict__ x,
                                           const ushort* __restrict__ w1b,
                                           const float* __restrict__ b1,
                                           const float* __restrict__ W2,
                                           float* __restrict__ out,
                                           float* __restrict__ ws) {
    constexpr bool DO_STAGE = (V == 0 || V == 1 || V == 3);
    constexpr bool DO_MFMA  = (V == 0 || V == 3);
    constexpr bool DO_EPI   = (V == 0 || V == 4);

    __shared__ __attribute__((aligned(16))) ushort smem[26624];   // 53248 B
    ushort* A0 = smem;
    ushort* A1 = smem + A_SZ;
    ushort* B0 = smem + 2 * A_SZ;
    ushort* B1 = smem + 2 * A_SZ + B_SZ;
    ushort* ldsH = smem;                                  // epilogue alias

    const int tid  = threadIdx.x;
    const int wave = tid >> 6;
    const int lane = tid & 63;
    const int r16  = lane & 15;
    const int kq   = lane >> 4;

    const int bid     = blockIdx.x;
    const int m       = bid & 7;                          // module -> XCD round-robin
    const int half    = (bid >> 3) & 1;                   // hidden half [half*256,+256)
    const int rowBase = (bid >> 4) * BM;

    const float*  xsrc = x + (size_t)rowBase * D_IN + m * DIM;
    const ushort* w1h  = w1b + (size_t)m * DIM * DIM + (size_t)half * BN * DIM;

    // staging thread mapping
    const int arow = tid >> 1;            // x: row 0..127
    const int ah   = tid & 1;             // x: 16-float half of the 32-float k-slice
    const int brow = tid >> 2;            // W: row within 64-row round
    const int bc   = tid & 3;             // W: 16B chunk 0..3

    float4v acc[8][4];
    if constexpr (DO_MFMA || V == 4) {
#pragma unroll
        for (int i = 0; i < 8; i++)
#pragma unroll
            for (int j = 0; j < 4; j++) acc[i][j] = (float4v){0.f, 0.f, 0.f, 0.f};
    }

    float4 xrA[4], xrB[4];                // 2-deep x register queue

    auto issueX = [&](int k, float4 (&xr)[4]) {
        const float* p = xsrc + (size_t)arow * D_IN + k * BK + ah * 16;
        xr[0] = *(const float4*)p;       xr[1] = *(const float4*)(p + 4);
        xr[2] = *(const float4*)(p + 8); xr[3] = *(const float4*)(p + 12);
    };
    auto issueW = [&](int k, ushort* Bn) {
#pragma unroll
        for (int r = 0; r < 4; r++) {
            const int row = r * 64 + brow;
            const int f   = (row >> 1) & 3;     // src-XOR so linear DMA dst reads conflict-free
            __builtin_amdgcn_global_load_lds(
                (const __attribute__((address_space(1))) void*)(w1h + (size_t)row * DIM + k * BK + (bc ^ f) * 8),
                (__attribute__((address_space(3))) void*)(Bn + row * BK + bc * 8), 16, 0, 0);
        }
    };
    auto writeA = [&](float4 (&xr)[4], ushort* An) {
        *(short8*)(An + arow * ASTRIDE + ah * 16)     = cvt8(xr[0], xr[1]);
        *(short8*)(An + arow * ASTRIDE + ah * 16 + 8) = cvt8(xr[2], xr[3]);
    };
    auto compute = [&](const ushort* Ac, const ushort* Bc) {
        short8 aF[8], bF[4];
#pragma unroll
        for (int mt = 0; mt < 8; mt++)
            aF[mt] = *(const short8*)(Ac + (mt * 16 + r16) * ASTRIDE + kq * 8);
#pragma unroll
        for (int nt = 0; nt < 4; nt++) {
            const int row = wave * 64 + nt * 16 + r16;
            bF[nt] = *(const short8*)(Bc + row * BK + (kq ^ ((row >> 1) & 3)) * 8);
        }
#pragma unroll
        for (int mt = 0; mt < 8; mt++)
#pragma unroll
            for (int nt = 0; nt < 4; nt++)
                acc[mt][nt] = __builtin_amdgcn_mfma_f32_16x16x32_bf16(aF[mt], bF[nt], acc[mt][nt], 0, 0, 0);
    };

    if constexpr (V != 4) {
        const int RREP = (V == 1 || V == 3) ? RP : 1;
        for (int rep = 0; rep < RREP; ++rep) {
            // ---- prologue. Issue order (pinned by fences): x(0), W(0), x(1). ----
            if constexpr (DO_STAGE) {
                issueX(0, xrA);  MEMFENCE();
                issueW(0, B0);   MEMFENCE();
                issueX(1, xrB);
                VMCNT(4);                   // x(0) AND W(0) done (cross-wave drain pre-barrier)
                writeA(xrA, A0);            // only wave-private x(1) in flight
            }
            LGKM0();
            __builtin_amdgcn_s_barrier();
            MEMFENCE();

            // Steady iter k: issue W(k+1), x(k+2); compute; VMCNT(4); writeA; lgkm; barrier.
            for (int k2 = 0; k2 < 14; k2 += 2) {
                {
                    if constexpr (DO_STAGE) {
                        issueW(k2 + 1, B1);  MEMFENCE();
                        issueX(k2 + 2, xrA); MEMFENCE();
                    }
                    if constexpr (DO_MFMA) compute(A0, B0);
                    MEMFENCE();
                    if constexpr (DO_STAGE) {
                        VMCNT(4);
                        writeA(xrB, A1);
                    }
                    LGKM0();
                    __builtin_amdgcn_s_barrier();
                    MEMFENCE();
                }
                {
                    if constexpr (DO_STAGE) {
                        issueW(k2 + 2, B0);  MEMFENCE();
                        issueX(k2 + 3, xrB); MEMFENCE();
                    }
                    if constexpr (DO_MFMA) compute(A1, B1);
                    MEMFENCE();
                    if constexpr (DO_STAGE) {
                        VMCNT(4);
                        writeA(xrA, A0);
                    }
                    LGKM0();
                    __builtin_amdgcn_s_barrier();
                    MEMFENCE();
                }
            }
            { // ---- k = 14 ----
                if constexpr (DO_STAGE) { issueW(15, B1);  MEMFENCE(); }
                if constexpr (DO_MFMA) compute(A0, B0);
                MEMFENCE();
                if constexpr (DO_STAGE) {
                    VMCNT(0);                         // tail drain -> clean slate per rep
                    writeA(xrB, A1);
                }
                LGKM0();
                __builtin_amdgcn_s_barrier();
                MEMFENCE();
            }
            { // ---- k = 15 ----
                if constexpr (DO_MFMA) compute(A1, B1);
                MEMFENCE();
            }
        }
    }

    if constexpr (!DO_EPI) {
        // ---- ablation dump: keep everything live, minimal extra work ----
        float s = 0.f;
        if constexpr (DO_MFMA) {
#pragma unroll
            for (int i = 0; i < 8; i++)
#pragma unroll
                for (int j = 0; j < 4; j++)
                    s += acc[i][j][0] + acc[i][j][1] + acc[i][j][2] + acc[i][j][3];
        } else {
            s = (float)A0[tid] + (float)A1[tid] + (float)B0[tid] + (float)B1[tid];
        }
        ws[(size_t)bid * 256 + tid] = s;
        return;
    }

    float b1v[4];
#pragma unroll
    for (int nt = 0; nt < 4; nt++)
        b1v[nt] = b1[m * DIM + half * BN + wave * 64 + nt * 16 + r16];

    // ---- epilogue: two 64-row halves; h -> ldsH (bias+relu bf16); fused layer-2 partial ----
    const int EREP = (V == 4) ? RP : 1;
    for (int er = 0; er < EREP; ++er) {
        for (int hh = 0; hh < 2; hh++) {
            __syncthreads();                  // K-loop frag reads / prev layer-2 reads done
#pragma unroll
            for (int mt2 = 0; mt2 < 4; mt2++) {
                const int mt = hh * 4 + mt2;
#pragma unroll
                for (int nt = 0; nt < 4; nt++) {
#pragma unroll
                    for (int reg = 0; reg < 4; reg++) {
                        float v = acc[mt][nt][reg] + b1v[nt];
                        v = v > 0.f ? v : 0.f;
                        const int lr  = mt2 * 16 + kq * 4 + reg;      // local batch row 0..63
                        const int col = wave * 64 + nt * 16 + r16;    // hidden col within half
                        ldsH[lr * HSTRIDE + col] = f2bf(v);
                    }
                }
            }
            __syncthreads();

            // layer 2 partial: y[64][10] += h[64][256] @ W2_half^T; 4 waves x 16 rows
            {
                float4v acc2 = (float4v){0.f, 0.f, 0.f, 0.f};
                const int hrow = wave * 16 + r16;
                const float* w2row = W2 + (size_t)(m * OSZ + r16) * D_IN + m * DIM + half * BN;
#pragma unroll
                for (int kc = 0; kc < BN / 32; kc++) {
                    const int c = kc * 32 + kq * 8;
                    short8 hA = *(const short8*)(ldsH + hrow * HSTRIDE + c);
                    short8 wb = {0, 0, 0, 0, 0, 0, 0, 0};
                    if (r16 < OSZ) {
                        const float* p = w2row + c;
                        wb = cvt8(*(const float4*)p, *(const float4*)(p + 4));
                    }
                    acc2 = __builtin_amdgcn_mfma_f32_16x16x32_bf16(hA, wb, acc2, 0, 0, 0);
                }
                if (r16 < OSZ) {
#pragma unroll
                    for (int reg = 0; reg < 4; reg++) {
                        const int grow = rowBase + hh * 64 + wave * 16 + kq * 4 + reg;
                        atomicAdd(out + (size_t)grow * D_OUT + m * OSZ + r16, acc2[reg]);
                    }
                }
            }
        }
    }
}

// ---- distinct kernel names so rocprof rows are unambiguous ----
__global__ __launch_bounds__(256, 2)
void fused_pipe(const float* __restrict__ x, const ushort* __restrict__ w1b,
                const float* __restrict__ b1, const float* __restrict__ W2,
                float* __restrict__ out) {
    fused_body<0, 1>(x, w1b, b1, W2, out, nullptr);
}
__global__ __launch_bounds__(256, 2)
void abl1_stage(const float* __restrict__ x, const ushort* __restrict__ w1b,
                const float* __restrict__ b1, const float* __restrict__ W2,
                float* __restrict__ ws) {
    fused_body<1, 3>(x, w1b, b1, W2, nullptr, ws);
}
__global__ __launch_bounds__(256, 2)
void abl3_noepi(const float* __restrict__ x, const ushort* __restrict__ w1b,
                const float* __restrict__ b1, const float* __restrict__ W2,
                float* __restrict__ ws) {
    fused_body<3, 3>(x, w1b, b1, W2, nullptr, ws);
}
__global__ __launch_bounds__(256, 2)
void abl4_epi(const float* __restrict__ x, const ushort* __restrict__ w1b,
              const float* __restrict__ b1, const float* __restrict__ W2,
              float* __restrict__ wsout) {
    fused_body<4, 6>(x, w1b, b1, W2, wsout, nullptr);
}

// ---------------- legacy fused kernel (tier C fallback, R5 structure) ----------------
__global__ __launch_bounds__(256, 2)
void fused_kernel(const float* __restrict__ x, const float* __restrict__ W1,
                  const float* __restrict__ b1, const float* __restrict__ W2,
                  float* __restrict__ out) {
    __shared__ __attribute__((aligned(16))) ushort smem[26624];   // 53248 B
    ushort* ldsA0 = smem;
    ushort* ldsA1 = smem + LDSA_SZ;
    ushort* ldsB0 = smem + 2 * LDSA_SZ;
    ushort* ldsB1 = smem + 2 * LDSA_SZ + LDSB_SZ;
    ushort* ldsH  = smem;

    const int tid  = threadIdx.x;
    const int wave = tid >> 6;
    const int lane = tid & 63;
    const int r16  = lane & 15;
    const int kq   = lane >> 4;

    const int bid     = blockIdx.x;
    const int m       = bid & 7;
    const int half    = (bid >> 3) & 1;
    const int rowBase = (bid >> 4) * BM;

    const float*  xsrc = x + (size_t)rowBase * D_IN + m * DIM;
    const float*  w1f  = W1 + (size_t)(m * DIM + half * BN) * D_IN + m * DIM;

    const int arow = tid >> 1;
    const int ah   = tid & 1;
    const int brow = tid >> 2;
    const int bc   = tid & 3;

    float4v acc[8][4];
#pragma unroll
    for (int i = 0; i < 8; i++)
#pragma unroll
        for (int j = 0; j < 4; j++) acc[i][j] = (float4v){0.f, 0.f, 0.f, 0.f};

#pragma unroll
    for (int r = 0; r < 4; r++) {
        const int row = r * 64 + brow;
        const int f   = (row >> 1) & 3;
        const float* p = w1f + (size_t)row * D_IN + bc * 8;
        *(short8*)(ldsB0 + row * BK + (bc ^ f) * 8) = cvt8(*(const float4*)p, *(const float4*)(p + 4));
    }
    {
        const float* p = xsrc + (size_t)arow * D_IN + ah * 16;
        float4 a0 = *(const float4*)p, a1 = *(const float4*)(p + 4);
        float4 a2 = *(const float4*)(p + 8), a3 = *(const float4*)(p + 12);
        *(short8*)(ldsA0 + arow * ASTRIDE + ah * 16)     = cvt8(a0, a1);
        *(short8*)(ldsA0 + arow * ASTRIDE + ah * 16 + 8) = cvt8(a2, a3);
    }

    for (int kk = 0; kk < NK; kk++) {
        __syncthreads();
        ushort* Ac = (kk & 1) ? ldsA1 : ldsA0;
        ushort* Bc = (kk & 1) ? ldsB1 : ldsB0;
        ushort* An = (kk & 1) ? ldsA0 : ldsA1;
        ushort* Bn = (kk & 1) ? ldsB0 : ldsB1;

        float4 xr0, xr1, xr2, xr3;
        const bool pf = (kk < NK - 1);
        if (pf) {
            const float* p = xsrc + (size_t)arow * D_IN + kk * BK + BK + ah * 16;
            xr0 = *(const float4*)p;     xr1 = *(const float4*)(p + 4);
            xr2 = *(const float4*)(p + 8); xr3 = *(const float4*)(p + 12);
        }

        short8 aF[8], bF[4];
#pragma unroll
        for (int mt = 0; mt < 8; mt++)
            aF[mt] = *(const short8*)(Ac + (mt * 16 + r16) * ASTRIDE + kq * 8);
#pragma unroll
        for (int nt = 0; nt < 4; nt++) {
            const int row = wave * 64 + nt * 16 + r16;
            bF[nt] = *(const short8*)(Bc + row * BK + (kq ^ ((row >> 1) & 3)) * 8);
        }
#pragma unroll
        for (int mt = 0; mt < 8; mt++)
#pragma unroll
            for (int nt = 0; nt < 4; nt++)
                acc[mt][nt] = __builtin_amdgcn_mfma_f32_16x16x32_bf16(aF[mt], bF[nt], acc[mt][nt], 0, 0, 0);

        if (pf) {
            *(short8*)(An + arow * ASTRIDE + ah * 16)     = cvt8(xr0, xr1);
            *(short8*)(An + arow * ASTRIDE + ah * 16 + 8) = cvt8(xr2, xr3);
#pragma unroll
            for (int r = 0; r < 4; r++) {
                const int row = r * 64 + brow;
                const int f   = (row >> 1) & 3;
                const float* p = w1f + (size_t)row * D_IN + kk * BK + BK + bc * 8;
                *(short8*)(Bn + row * BK + (bc ^ f) * 8) = cvt8(*(const float4*)p, *(const float4*)(p + 4));
            }
        }
    }

    float b1v[4];
#pragma unroll
    for (int nt = 0; nt < 4; nt++)
        b1v[nt] = b1[m * DIM + half * BN + wave * 64 + nt * 16 + r16];

    for (int hh = 0; hh < 2; hh++) {
        __syncthreads();
#pragma unroll
        for (int mt2 = 0; mt2 < 4; mt2++) {
            const int mt = hh * 4 + mt2;
#pragma unroll
            for (int nt = 0; nt < 4; nt++) {
#pragma unroll
                for (int reg = 0; reg < 4; reg++) {
                    float v = acc[mt][nt][reg] + b1v[nt];
                    v = v > 0.f ? v : 0.f;
                    const int lr  = mt2 * 16 + kq * 4 + reg;
                    const int col = wave * 64 + nt * 16 + r16;
                    ldsH[lr * HSTRIDE + col] = f2bf(v);
                }
            }
        }
        __syncthreads();

        {
            float4v acc2 = (float4v){0.f, 0.f, 0.f, 0.f};
            const int hrow = wave * 16 + r16;
            const float* w2row = W2 + (size_t)(m * OSZ + r16) * D_IN + m * DIM + half * BN;
#pragma unroll
            for (int kc = 0; kc < BN / 32; kc++) {
                const int c = kc * 32 + kq * 8;
                short8 hA = *(const short8*)(ldsH + hrow * HSTRIDE + c);
                short8 wb = {0, 0, 0, 0, 0, 0, 0, 0};
                if (r16 < OSZ) {
                    const float* p = w2row + c;
                    wb = cvt8(*(const float4*)p, *(const float4*)(p + 4));
                }
                acc2 = __builtin_amdgcn_mfma_f32_16x16x32_bf16(hA, wb, acc2, 0, 0, 0);
            }
            if (r16 < OSZ) {
#pragma unroll
                for (int reg = 0; reg < 4; reg++) {
                    const int grow = rowBase + hh * 64 + wave * 16 + kq * 4 + reg;
                    atomicAdd(out + (size_t)grow * D_OUT + m * OSZ + r16, acc2[reg]);
                }
            }
        }
    }
}

extern "C" void kernel_launch(void* const* d_in, const int* in_sizes, int n_in,
                              void* d_out, int out_size, void* d_ws, size_t ws_size,
                              hipStream_t stream) {
    const float* x  = (const float*)d_in[0];
    const float* W1 = (const float*)d_in[1];
    const float* b1 = (const float*)d_in[2];
    const float* W2 = (const float*)d_in[3];
    const float* b2 = (const float*)d_in[4];
    float* out = (float*)d_out;

    if (ws_size >= (size_t)NMOD * DIM * DIM * sizeof(ushort)) {   // 4 MB: tier B
        ushort* w1b = (ushort*)d_ws;
        float*  wsf = (float*)d_ws;
        // ---- diagnostic ablations (garbage w1b is fine for timing; all ws writes land in
        //      the first 4 MB and are overwritten by cvt_w before fused_pipe reads w1b). ----
        abl1_stage<<<dim3(1024), dim3(256), 0, stream>>>(x, w1b, b1, W2, wsf + 720896);
        abl3_noepi<<<dim3(1024), dim3(256), 0, stream>>>(x, w1b, b1, W2, wsf + 0);
        abl4_epi  <<<dim3(1024), dim3(256), 0, stream>>>(x, w1b, b1, W2, wsf + 0);
        // ---- real pipeline (R8-exact) ----
        init_out_kernel<<<dim3(2560), dim3(256), 0, stream>>>(b2, out);
        cvt_w_kernel<<<dim3(2048), dim3(256), 0, stream>>>(W1, w1b);
        fused_pipe<<<dim3(1024), dim3(256), 0, stream>>>(x, w1b, b1, W2, out);
    } else {                                                      // tier C: zero workspace
        init_out_kernel<<<dim3(2560), dim3(256), 0, stream>>>(b2, out);
        fused_kernel<<<dim3(1024), dim3(256), 0, stream>>>(x, W1, b1, W2, out);
    }
}

// Round 10
// 256.969 us; speedup vs baseline: 2.2270x; 2.2270x over previous
//
#include <hip/hip_runtime.h>

// Modular readout: 8 modules, each h = relu(x_m @ W1_m^T + b1_m); y_m = h @ W2_m^T + b2_m
// x [8192,4096] fp32; W1 [4096,4096] fp32 block-diag (8x 512x512); W2 [80,4096] fp32 block-diag
// out [8192,80] fp32 row-major (module-major columns).
//
// R15: R14 ablation resolved the wall: staging ALONE = 45us/rep (MfmaUtil 0, 1.46/6.3 TB/s,
//      requests ~0.009/cy/CU) while staging+MFMA is NO SLOWER -> K-loop is 100% staging-
//      latency-bound. The exposed chain is R8's same-iteration W drain (VMCNT(4) pre-barrier,
//      forced by the cross-wave race rule): one full L2/L3 latency per iteration, serialized
//      by the barrier. Fix = depth, made legal by OWNERSHIP:
//  - Wave-private B staging: wave w DMAs exactly the 64 B-rows it reads -> produce/consume
//    is wave-local -> NO barrier/no pre-barrier drain for W. Wait is wave-local counted
//    VMCNT(12) before the ds_read of B(k), for a DMA issued TWO iterations earlier.
//  - Steady queue invariant (oldest first): [W(k)4, x(k+1)4, W(k+1)4] = 12 at iter top.
//    Per iter: issueX(k+2); read aF; VMCNT(12) [W(k) done]; read bF; lgkm0; issueW(k+2)
//    into the just-read buffer; MFMA; VMCNT(12) [x(k+1) done]; writeA; lgkm0; s_barrier.
//    Only cross-wave resource is A (x-tile): its data is reg-waited + lgkm-drained pre-barrier.
//  - LDS identical to R8 (53248 B: 2xA + 2xB), same conflict-free layouts (ASTRIDE 40,
//    B src-XOR). Single-variant build (ablations removed - rule #19 codegen perturbation).
//  - Epilogue unchanged (<=22us by R14 ablation; attack next if loop drops).

#define NMOD 8
#define DIM 512
#define OSZ 10
#define BATCH 8192
#define D_IN 4096
#define D_OUT 80
#define BM 128
#define BN 256
#define BK 32
#define NK (DIM / BK)     // 16

#define ASTRIDE 40        // ldsA row stride (shorts); 80B, 16B-aligned, conflict-free
#define HSTRIDE 264       // ldsH row stride (shorts); 528B = 33*16 -> aligned + conflict-free
#define A_SZ 5120         // 128*40 shorts per A buffer (10240 B)
#define B_SZ 8192         // 256*32 shorts per B buffer (16384 B, unpadded: DMA lane-contiguous dst)

// legacy tier-C sizes
#define LDSA_SZ 5120
#define LDSB_SZ 8192

#define VMCNT(n) asm volatile("s_waitcnt vmcnt(" #n ")" ::: "memory")
#define LGKM0()  asm volatile("s_waitcnt lgkmcnt(0)" ::: "memory")
#define MEMFENCE() asm volatile("" ::: "memory")

typedef __attribute__((ext_vector_type(8))) short short8;   // 8 bf16 MFMA A/B frag
typedef __attribute__((ext_vector_type(4))) float float4v;  // MFMA C/D frag
typedef __attribute__((ext_vector_type(4))) unsigned int uint4v;

__device__ __forceinline__ unsigned short f2bf(float f) {
    unsigned int u = __builtin_bit_cast(unsigned int, f);
    u += 0x7fffu + ((u >> 16) & 1u);   // RNE
    return (unsigned short)(u >> 16);
}

__device__ __forceinline__ unsigned int pk2(float a, float b) {
    unsigned int r;
    asm("v_cvt_pk_bf16_f32 %0, %1, %2" : "=v"(r) : "v"(a), "v"(b));
    return r;
}

// packed f32x8 -> bf16x8 via HW cvt_pk (RNE, same numerics as f2bf)
__device__ __forceinline__ short8 cvt8(float4 a, float4 b) {
    uint4v u = {pk2(a.x, a.y), pk2(a.z, a.w), pk2(b.x, b.y), pk2(b.z, b.w)};
    return __builtin_bit_cast(short8, u);
}

// ------- init: out = broadcast b2 (atomicAdd accumulation base) -------
__global__ void init_out_kernel(const float* __restrict__ b2, float* __restrict__ out) {
    int idx = blockIdx.x * 256 + threadIdx.x;            // 2560*256 = 655360 = 8192*80
    out[idx] = b2[idx % D_OUT];
}

// ------- tier B: gather W1 diag blocks -> w1b[8][512][512] bf16 (4 MB) -------
__global__ void cvt_w_kernel(const float* __restrict__ W1, ushort* __restrict__ w1b) {
    int j = blockIdx.x * 256 + threadIdx.x;              // 2048*256 = 524288 float4 jobs
    int mm = j >> 16, rem = j & 65535, r = rem >> 7, c4 = rem & 127;
    float4 v = *(const float4*)(W1 + (size_t)(mm * DIM + r) * D_IN + mm * DIM + c4 * 4);
    *(ushort4*)(w1b + (size_t)mm * DIM * DIM + r * DIM + c4 * 4) =
        make_ushort4(f2bf(v.x), f2bf(v.y), f2bf(v.z), f2bf(v.w));
}

// ---------------- R15 deep-pipelined fused kernel (tier B) ----------------
// grid 1024: bid = tile*16 + half*8 + m. block 256 (4 waves), wave w: hidden cols [w*64,+64),
// all 128 batch rows (acc[8][4] = 128 regs).
// LDS (shorts): A0@0, A1@5120, B0@10240, B1@18432 (53248 B); ldsH [64][264] @0 (aliased).
__global__ __launch_bounds__(256, 2)
void fused_pipe(const float* __restrict__ x, const ushort* __restrict__ w1b,
                const float* __restrict__ b1, const float* __restrict__ W2,
                float* __restrict__ out) {
    __shared__ __attribute__((aligned(16))) ushort smem[26624];   // 53248 B
    ushort* A0 = smem;
    ushort* A1 = smem + A_SZ;
    ushort* B0 = smem + 2 * A_SZ;
    ushort* B1 = smem + 2 * A_SZ + B_SZ;
    ushort* ldsH = smem;                                  // epilogue alias

    const int tid  = threadIdx.x;
    const int wave = tid >> 6;
    const int lane = tid & 63;
    const int r16  = lane & 15;
    const int kq   = lane >> 4;

    const int bid     = blockIdx.x;
    const int m       = bid & 7;                          // module -> XCD round-robin
    const int half    = (bid >> 3) & 1;                   // hidden half [half*256,+256)
    const int rowBase = (bid >> 4) * BM;

    const float*  xsrc = x + (size_t)rowBase * D_IN + m * DIM;
    const ushort* w1h  = w1b + (size_t)m * DIM * DIM + (size_t)half * BN * DIM;

    // staging thread mapping
    const int arow = tid >> 1;            // x: row 0..127
    const int ah   = tid & 1;             // x: 16-float half of the 32-float k-slice
    const int bl4  = lane >> 2;           // W: row sub-index within 16-row strip
    const int bc   = lane & 3;            // W: 16B chunk 0..3

    float4v acc[8][4];
#pragma unroll
    for (int i = 0; i < 8; i++)
#pragma unroll
        for (int j = 0; j < 4; j++) acc[i][j] = (float4v){0.f, 0.f, 0.f, 0.f};

    float4 xrA[4], xrB[4];                // 2-deep x register queue (even k -> xrA, odd -> xrB)

    auto issueX = [&](int k, float4 (&xr)[4]) {
        const float* p = xsrc + (size_t)arow * D_IN + k * BK + ah * 16;
        xr[0] = *(const float4*)p;       xr[1] = *(const float4*)(p + 4);
        xr[2] = *(const float4*)(p + 8); xr[3] = *(const float4*)(p + 12);
    };
    // wave-PRIVATE B staging: wave w DMAs rows [w*64, +64) -- exactly the rows it reads.
    // dst = Bn + row*BK + bc*8 shorts; per instr: base + lane*16B (lane-contiguous) ✓
    auto issueW = [&](int k, ushort* Bn) {
#pragma unroll
        for (int r = 0; r < 4; r++) {
            const int row = wave * 64 + r * 16 + bl4;
            const int f   = (row >> 1) & 3;     // src-XOR so linear DMA dst reads conflict-free
            __builtin_amdgcn_global_load_lds(
                (const __attribute__((address_space(1))) void*)(w1h + (size_t)row * DIM + k * BK + (bc ^ f) * 8),
                (__attribute__((address_space(3))) void*)(Bn + row * BK + bc * 8), 16, 0, 0);
        }
    };
    auto writeA = [&](float4 (&xr)[4], ushort* An) {
        *(short8*)(An + arow * ASTRIDE + ah * 16)     = cvt8(xr[0], xr[1]);
        *(short8*)(An + arow * ASTRIDE + ah * 16 + 8) = cvt8(xr[2], xr[3]);
    };

    short8 aF[8], bF[4];
    auto readA = [&](const ushort* Ac) {
#pragma unroll
        for (int mt = 0; mt < 8; mt++)
            aF[mt] = *(const short8*)(Ac + (mt * 16 + r16) * ASTRIDE + kq * 8);
    };
    auto readB = [&](const ushort* Bc) {
#pragma unroll
        for (int nt = 0; nt < 4; nt++) {
            const int row = wave * 64 + nt * 16 + r16;
            bF[nt] = *(const short8*)(Bc + row * BK + (kq ^ ((row >> 1) & 3)) * 8);
        }
    };
    auto mfma = [&]() {
#pragma unroll
        for (int mt = 0; mt < 8; mt++)
#pragma unroll
            for (int nt = 0; nt < 4; nt++)
                acc[mt][nt] = __builtin_amdgcn_mfma_f32_16x16x32_bf16(aF[mt], bF[nt], acc[mt][nt], 0, 0, 0);
    };

    // ---- prologue. Issue order (pinned): x(0), W(0)->B0, x(1), W(1)->B1. ----
    issueX(0, xrA);  MEMFENCE();
    issueW(0, B0);   MEMFENCE();
    issueX(1, xrB);  MEMFENCE();
    issueW(1, B1);
    VMCNT(12);                          // x(0) done; [W(0), x(1), W(1)] = 12 in flight
    writeA(xrA, A0);
    LGKM0();
    __builtin_amdgcn_s_barrier();
    MEMFENCE();

    // Steady iter k (invariant at top, oldest first): [W(k)4, x(k+1)4, W(k+1)4] = 12.
    //   issueX(k+2) -> 16; read aF; VMCNT(12) drains W(k) (2-iter depth, wave-local);
    //   read bF; LGKM0; issueW(k+2) into just-read buf -> 16; MFMA;
    //   VMCNT(12) drains x(k+1) (1-iter depth); writeA; LGKM0; s_barrier -> invariant.
#define STEADY_ITER(KP2, Ac, Bc, An, XRD, XRI)                                 \
    do {                                                                       \
        issueX((KP2), (XRI)); MEMFENCE();                                      \
        readA((Ac));                                                           \
        VMCNT(12);                                                             \
        readB((Bc));                                                           \
        LGKM0();                                                               \
        issueW((KP2), (Bc)); MEMFENCE();                                       \
        mfma();                                                                \
        MEMFENCE();                                                            \
        VMCNT(12);                                                             \
        writeA((XRD), (An));                                                   \
        LGKM0();                                                               \
        __builtin_amdgcn_s_barrier();                                          \
        MEMFENCE();                                                            \
    } while (0)

    for (int k2 = 0; k2 < 14; k2 += 2) {
        STEADY_ITER(k2 + 2, A0, B0, A1, xrB, xrA);   // even k: consume A0/B0; W(k+2)->B0
        STEADY_ITER(k2 + 3, A1, B1, A0, xrA, xrB);   // odd  k: consume A1/B1; W(k+3)->B1
    }
#undef STEADY_ITER
    { // ---- k = 14: no new issues. Top: [W(14), x(15), W(15)] = 12. ----
        readA(A0);
        VMCNT(8);                         // drain W(14); [x(15), W(15)] left
        readB(B0);
        LGKM0();
        mfma();
        MEMFENCE();
        VMCNT(4);                         // drain x(15); [W(15)] left
        writeA(xrB, A1);
        LGKM0();
        __builtin_amdgcn_s_barrier();
        MEMFENCE();
    }
    { // ---- k = 15: last. ----
        readA(A1);
        VMCNT(0);                         // drain W(15)
        readB(B1);
        LGKM0();
        mfma();
        MEMFENCE();
    }

    float b1v[4];
#pragma unroll
    for (int nt = 0; nt < 4; nt++)
        b1v[nt] = b1[m * DIM + half * BN + wave * 64 + nt * 16 + r16];

    // ---- epilogue: two 64-row halves; h -> ldsH (bias+relu bf16); fused layer-2 partial ----
    for (int hh = 0; hh < 2; hh++) {
        __syncthreads();                      // K-loop frag reads / prev layer-2 reads done
#pragma unroll
        for (int mt2 = 0; mt2 < 4; mt2++) {
            const int mt = hh * 4 + mt2;
#pragma unroll
            for (int nt = 0; nt < 4; nt++) {
#pragma unroll
                for (int reg = 0; reg < 4; reg++) {
                    float v = acc[mt][nt][reg] + b1v[nt];
                    v = v > 0.f ? v : 0.f;
                    const int lr  = mt2 * 16 + kq * 4 + reg;          // local batch row 0..63
                    const int col = wave * 64 + nt * 16 + r16;        // hidden col within half
                    ldsH[lr * HSTRIDE + col] = f2bf(v);
                }
            }
        }
        __syncthreads();

        // layer 2 partial: y[64][10] += h[64][256] @ W2_half^T; 4 waves x 16 rows
        {
            float4v acc2 = (float4v){0.f, 0.f, 0.f, 0.f};
            const int hrow = wave * 16 + r16;
            const float* w2row = W2 + (size_t)(m * OSZ + r16) * D_IN + m * DIM + half * BN;
#pragma unroll
            for (int kc = 0; kc < BN / 32; kc++) {
                const int c = kc * 32 + kq * 8;
                short8 hA = *(const short8*)(ldsH + hrow * HSTRIDE + c);
                short8 wb = {0, 0, 0, 0, 0, 0, 0, 0};
                if (r16 < OSZ) {
                    const float* p = w2row + c;
                    wb = cvt8(*(const float4*)p, *(const float4*)(p + 4));
                }
                acc2 = __builtin_amdgcn_mfma_f32_16x16x32_bf16(hA, wb, acc2, 0, 0, 0);
            }
            if (r16 < OSZ) {
#pragma unroll
                for (int reg = 0; reg < 4; reg++) {
                    const int grow = rowBase + hh * 64 + wave * 16 + kq * 4 + reg;
                    atomicAdd(out + (size_t)grow * D_OUT + m * OSZ + r16, acc2[reg]);
                }
            }
        }
    }
}

// ---------------- legacy fused kernel (tier C fallback, R5 structure) ----------------
__global__ __launch_bounds__(256, 2)
void fused_kernel(const float* __restrict__ x, const float* __restrict__ W1,
                  const float* __restrict__ b1, const float* __restrict__ W2,
                  float* __restrict__ out) {
    __shared__ __attribute__((aligned(16))) ushort smem[26624];   // 53248 B
    ushort* ldsA0 = smem;
    ushort* ldsA1 = smem + LDSA_SZ;
    ushort* ldsB0 = smem + 2 * LDSA_SZ;
    ushort* ldsB1 = smem + 2 * LDSA_SZ + LDSB_SZ;
    ushort* ldsH  = smem;

    const int tid  = threadIdx.x;
    const int wave = tid >> 6;
    const int lane = tid & 63;
    const int r16  = lane & 15;
    const int kq   = lane >> 4;

    const int bid     = blockIdx.x;
    const int m       = bid & 7;
    const int half    = (bid >> 3) & 1;
    const int rowBase = (bid >> 4) * BM;

    const float*  xsrc = x + (size_t)rowBase * D_IN + m * DIM;
    const float*  w1f  = W1 + (size_t)(m * DIM + half * BN) * D_IN + m * DIM;

    const int arow = tid >> 1;
    const int ah   = tid & 1;
    const int brow = tid >> 2;
    const int bc   = tid & 3;

    float4v acc[8][4];
#pragma unroll
    for (int i = 0; i < 8; i++)
#pragma unroll
        for (int j = 0; j < 4; j++) acc[i][j] = (float4v){0.f, 0.f, 0.f, 0.f};

#pragma unroll
    for (int r = 0; r < 4; r++) {
        const int row = r * 64 + brow;
        const int f   = (row >> 1) & 3;
        const float* p = w1f + (size_t)row * D_IN + bc * 8;
        *(short8*)(ldsB0 + row * BK + (bc ^ f) * 8) = cvt8(*(const float4*)p, *(const float4*)(p + 4));
    }
    {
        const float* p = xsrc + (size_t)arow * D_IN + ah * 16;
        float4 a0 = *(const float4*)p, a1 = *(const float4*)(p + 4);
        float4 a2 = *(const float4*)(p + 8), a3 = *(const float4*)(p + 12);
        *(short8*)(ldsA0 + arow * ASTRIDE + ah * 16)     = cvt8(a0, a1);
        *(short8*)(ldsA0 + arow * ASTRIDE + ah * 16 + 8) = cvt8(a2, a3);
    }

    for (int kk = 0; kk < NK; kk++) {
        __syncthreads();
        ushort* Ac = (kk & 1) ? ldsA1 : ldsA0;
        ushort* Bc = (kk & 1) ? ldsB1 : ldsB0;
        ushort* An = (kk & 1) ? ldsA0 : ldsA1;
        ushort* Bn = (kk & 1) ? ldsB0 : ldsB1;

        float4 xr0, xr1, xr2, xr3;
        const bool pf = (kk < NK - 1);
        if (pf) {
            const float* p = xsrc + (size_t)arow * D_IN + kk * BK + BK + ah * 16;
            xr0 = *(const float4*)p;     xr1 = *(const float4*)(p + 4);
            xr2 = *(const float4*)(p + 8); xr3 = *(const float4*)(p + 12);
        }

        short8 aF[8], bF[4];
#pragma unroll
        for (int mt = 0; mt < 8; mt++)
            aF[mt] = *(const short8*)(Ac + (mt * 16 + r16) * ASTRIDE + kq * 8);
#pragma unroll
        for (int nt = 0; nt < 4; nt++) {
            const int row = wave * 64 + nt * 16 + r16;
            bF[nt] = *(const short8*)(Bc + row * BK + (kq ^ ((row >> 1) & 3)) * 8);
        }
#pragma unroll
        for (int mt = 0; mt < 8; mt++)
#pragma unroll
            for (int nt = 0; nt < 4; nt++)
                acc[mt][nt] = __builtin_amdgcn_mfma_f32_16x16x32_bf16(aF[mt], bF[nt], acc[mt][nt], 0, 0, 0);

        if (pf) {
            *(short8*)(An + arow * ASTRIDE + ah * 16)     = cvt8(xr0, xr1);
            *(short8*)(An + arow * ASTRIDE + ah * 16 + 8) = cvt8(xr2, xr3);
#pragma unroll
            for (int r = 0; r < 4; r++) {
                const int row = r * 64 + brow;
                const int f   = (row >> 1) & 3;
                const float* p = w1f + (size_t)row * D_IN + kk * BK + BK + bc * 8;
                *(short8*)(Bn + row * BK + (bc ^ f) * 8) = cvt8(*(const float4*)p, *(const float4*)(p + 4));
            }
        }
    }

    float b1v[4];
#pragma unroll
    for (int nt = 0; nt < 4; nt++)
        b1v[nt] = b1[m * DIM + half * BN + wave * 64 + nt * 16 + r16];

    for (int hh = 0; hh < 2; hh++) {
        __syncthreads();
#pragma unroll
        for (int mt2 = 0; mt2 < 4; mt2++) {
            const int mt = hh * 4 + mt2;
#pragma unroll
            for (int nt = 0; nt < 4; nt++) {
#pragma unroll
                for (int reg = 0; reg < 4; reg++) {
                    float v = acc[mt][nt][reg] + b1v[nt];
                    v = v > 0.f ? v : 0.f;
                    const int lr  = mt2 * 16 + kq * 4 + reg;
                    const int col = wave * 64 + nt * 16 + r16;
                    ldsH[lr * HSTRIDE + col] = f2bf(v);
                }
            }
        }
        __syncthreads();

        {
            float4v acc2 = (float4v){0.f, 0.f, 0.f, 0.f};
            const int hrow = wave * 16 + r16;
            const float* w2row = W2 + (size_t)(m * OSZ + r16) * D_IN + m * DIM + half * BN;
#pragma unroll
            for (int kc = 0; kc < BN / 32; kc++) {
                const int c = kc * 32 + kq * 8;
                short8 hA = *(const short8*)(ldsH + hrow * HSTRIDE + c);
                short8 wb = {0, 0, 0, 0, 0, 0, 0, 0};
                if (r16 < OSZ) {
                    const float* p = w2row + c;
                    wb = cvt8(*(const float4*)p, *(const float4*)(p + 4));
                }
                acc2 = __builtin_amdgcn_mfma_f32_16x16x32_bf16(hA, wb, acc2, 0, 0, 0);
            }
            if (r16 < OSZ) {
#pragma unroll
                for (int reg = 0; reg < 4; reg++) {
                    const int grow = rowBase + hh * 64 + wave * 16 + kq * 4 + reg;
                    atomicAdd(out + (size_t)grow * D_OUT + m * OSZ + r16, acc2[reg]);
                }
            }
        }
    }
}

extern "C" void kernel_launch(void* const* d_in, const int* in_sizes, int n_in,
                              void* d_out, int out_size, void* d_ws, size_t ws_size,
                              hipStream_t stream) {
    const float* x  = (const float*)d_in[0];
    const float* W1 = (const float*)d_in[1];
    const float* b1 = (const float*)d_in[2];
    const float* W2 = (const float*)d_in[3];
    const float* b2 = (const float*)d_in[4];
    float* out = (float*)d_out;

    init_out_kernel<<<dim3(2560), dim3(256), 0, stream>>>(b2, out);

    if (ws_size >= (size_t)NMOD * DIM * DIM * sizeof(ushort)) {   // 4 MB: tier B (bf16 W1 + DMA)
        ushort* w1b = (ushort*)d_ws;
        cvt_w_kernel<<<dim3(2048), dim3(256), 0, stream>>>(W1, w1b);
        fused_pipe<<<dim3(1024), dim3(256), 0, stream>>>(x, w1b, b1, W2, out);
    } else {                                                      // tier C: zero workspace
        fused_kernel<<<dim3(1024), dim3(256), 0, stream>>>(x, W1, b1, W2, out);
    }
}